// Round 3
// baseline (2138.596 us; speedup 1.0000x reference)
//
#include <hip/hip_runtime.h>
#include <hip/hip_fp16.h>
#include <math.h>

typedef _Float16 h16;
typedef unsigned long long u64;
typedef __attribute__((ext_vector_type(8))) _Float16 half8;
typedef __attribute__((ext_vector_type(4))) float f32x4;

#define GLOAD_LDS16(gp, lp) __builtin_amdgcn_global_load_lds( \
    (const __attribute__((address_space(1))) void*)(gp),      \
    (__attribute__((address_space(3))) void*)(lp), 16, 0, 0)

// ===== old LDS-staged gemm core (used by k_xproj / k_head only) =============
union SmemGemm {
  h16   buf[2][96 * 128];
  float red[4][2048];
};

__device__ __forceinline__ void stage_tile(SmemGemm& sm, int b,
                                           const h16* __restrict__ Ag,
                                           const h16* __restrict__ Bg,
                                           int kk, int kdim, int wave, int lane) {
  h16* As = sm.buf[b];
  h16* Bs = As + 32 * 128;
  const int kb = kk * 128;
#pragma unroll
  for (int i = 0; i < 2; ++i) {
    const int id = wave * 2 + i;
    const int chunk = id * 64 + lane;
    GLOAD_LDS16(Ag + (long)(chunk >> 4) * kdim + kb + (chunk & 15) * 8,
                As + id * 512);
  }
#pragma unroll
  for (int i = 0; i < 4; ++i) {
    const int id = wave * 4 + i;
    const int chunk = id * 64 + lane;
    GLOAD_LDS16(Bg + (long)(chunk >> 4) * kdim + kb + (chunk & 15) * 8,
                Bs + id * 512);
  }
}

template <int KDIM>
__device__ __forceinline__ void gemm_core(SmemGemm& sm,
                                          const h16* __restrict__ Ag,
                                          const h16* __restrict__ Bg,
                                          int wave, int lane) {
  f32x4 acc[2][4];
#pragma unroll
  for (int a = 0; a < 2; ++a)
#pragma unroll
    for (int c = 0; c < 4; ++c) acc[a][c] = (f32x4){0.f, 0.f, 0.f, 0.f};

  const int mr = lane & 15, q = lane >> 4;
  constexpr int NIT = KDIM / 128;
  stage_tile(sm, 0, Ag, Bg, 0, KDIM, wave, lane);
  for (int kk = 0; kk < NIT; ++kk) {
    __syncthreads();
    if (kk + 1 < NIT) stage_tile(sm, (kk + 1) & 1, Ag, Bg, kk + 1, KDIM, wave, lane);
    const h16* As = sm.buf[kk & 1];
    const h16* Bs = As + 32 * 128;
    const int ko = wave * 32 + q * 8;
    half8 a0 = *(const half8*)(As + mr * 128 + ko);
    half8 a1 = *(const half8*)(As + (mr + 16) * 128 + ko);
#pragma unroll
    for (int fc = 0; fc < 4; ++fc) {
      half8 bv = *(const half8*)(Bs + (fc * 16 + mr) * 128 + ko);
      acc[0][fc] = __builtin_amdgcn_mfma_f32_16x16x32_f16(a0, bv, acc[0][fc], 0, 0, 0);
      acc[1][fc] = __builtin_amdgcn_mfma_f32_16x16x32_f16(a1, bv, acc[1][fc], 0, 0, 0);
    }
  }
  __syncthreads();
#pragma unroll
  for (int fr = 0; fr < 2; ++fr)
#pragma unroll
    for (int fc = 0; fc < 4; ++fc)
#pragma unroll
      for (int r = 0; r < 4; ++r)
        sm.red[wave][(fr * 16 + q * 4 + r) * 64 + fc * 16 + mr] = acc[fr][fc][r];
  __syncthreads();
}

__device__ __forceinline__ float fast_tanh(float x) {
  float e = __expf(2.0f * fabsf(x));
  float t = 1.0f - 2.0f / (e + 1.0f);
  return copysignf(t, x);
}

// ===== prep: sigma = ||W t|| / ||t||, t = W^T u =============================
__global__ void k_zero(float* t, float* sbuf, int* cnt) {
  const int i = threadIdx.x;
  for (int k = i; k < 1024; k += 256) t[k] = 0.f;
  if (i < 2) sbuf[i] = 0.f;
  cnt[i] = 0;
}

// 32 blocks x 256 thr: block b accumulates rows j in [64b, 64b+64) into t[k]
__global__ void __launch_bounds__(256)
k_prep1(const float* __restrict__ Win, const float* __restrict__ u,
        float* __restrict__ t) {
  const int k4 = threadIdx.x * 4;
  const int j0 = blockIdx.x * 64;
  f32x4 acc = (f32x4){0.f, 0.f, 0.f, 0.f};
  for (int j = j0; j < j0 + 64; ++j) {
    f32x4 wv = *(const f32x4*)&Win[(long)j * 1024 + k4];
    acc += wv * u[j];
  }
#pragma unroll
  for (int i = 0; i < 4; ++i) atomicAdd(&t[k4 + i], acc[i]);
}

__global__ void __launch_bounds__(256)
k_norm(const float* __restrict__ t, float* __restrict__ sbuf) {
  f32x4 v = *(const f32x4*)&t[threadIdx.x * 4];
  float s = v[0] * v[0] + v[1] * v[1] + v[2] * v[2] + v[3] * v[3];
#pragma unroll
  for (int off = 32; off > 0; off >>= 1) s += __shfl_down(s, off);
  if ((threadIdx.x & 63) == 0) atomicAdd(&sbuf[0], s);  // s1 = ||t||^2
}

__global__ void __launch_bounds__(256)
k_prep2(const float* __restrict__ Win, const float* __restrict__ t,
        float* __restrict__ sbuf) {
  const int row = blockIdx.x * 4 + (threadIdx.x >> 6);
  const int lane = threadIdx.x & 63;
  float acc = 0.f;
  for (int kk = lane; kk < 1024; kk += 64)
    acc = fmaf(Win[row * 1024 + kk], t[kk], acc);
#pragma unroll
  for (int off = 32; off > 0; off >>= 1) acc += __shfl_down(acc, off);
  if (lane == 0) atomicAdd(&sbuf[1], acc * acc);        // s2 = ||W t||^2
}

// ===== fp32 -> fp16 conversions =============================================
__global__ void __launch_bounds__(256)
k_cvt(const float* __restrict__ W0, const float* __restrict__ W1,
      const float* __restrict__ W2, const float* __restrict__ Win,
      const float* __restrict__ Hw, const float* __restrict__ X,
      h16* __restrict__ w16, h16* __restrict__ wi16,
      h16* __restrict__ hw16, h16* __restrict__ x16) {
  const long e = (long)(blockIdx.x * 256 + threadIdx.x) * 8;
  const float* src; h16* dst;
  if (e < 4194304)       { src = W0 + e;              dst = w16 + e; }
  else if (e < 8388608)  { src = W1 + (e - 4194304);  dst = w16 + e; }
  else if (e < 12582912) { src = W2 + (e - 8388608);  dst = w16 + e; }
  else if (e < 14680064) { src = Win + (e - 12582912); dst = wi16 + (e - 12582912); }
  else if (e < 16728064) { src = Hw + (e - 14680064);  dst = hw16 + (e - 14680064); }
  else if (e < 16777216) {
    half8 z = (half8){};
    *(half8*)(hw16 + 2048000 + (e - 16728064)) = z;
    return;
  }
  else                   { src = X + (e - 16777216);   dst = x16 + (e - 16777216); }
  f32x4 f0 = *(const f32x4*)src, f1 = *(const f32x4*)(src + 4);
  half8 h;
#pragma unroll
  for (int i = 0; i < 4; ++i) { h[i] = (h16)f0[i]; h[i + 4] = (h16)f1[i]; }
  *(half8*)dst = h;
}

// ===== x_proj = (x @ Win^T)/sigma + Win_b; zero hbuf[0] =====================
__global__ void __launch_bounds__(256)
k_xproj(const h16* __restrict__ x16, const h16* __restrict__ wi16,
        const float* __restrict__ Winb, const float* __restrict__ sbuf,
        float* __restrict__ xp, h16* __restrict__ h16a) {
  __shared__ SmemGemm sm;
  const int rb = blockIdx.x >> 5, cb = blockIdx.x & 31;
  const int wave = threadIdx.x >> 6, lane = threadIdx.x & 63;
  gemm_core<1024>(sm, x16 + rb * 32 * 1024, wi16 + (long)cb * 64 * 1024, wave, lane);
  const float inv_sigma = sqrtf(sbuf[0] / sbuf[1]);
  const int e = threadIdx.x * 8;
  const int gi = rb * 32 + (e >> 6), gj = cb * 64 + (e & 63);
  const long base = (long)gi * 2048 + gj;
  f32x4 s0 = *(const f32x4*)&sm.red[0][e], s1 = *(const f32x4*)&sm.red[0][e + 4];
#pragma unroll
  for (int w = 1; w < 4; ++w) {
    s0 += *(const f32x4*)&sm.red[w][e];
    s1 += *(const f32x4*)&sm.red[w][e + 4];
  }
  f32x4 b0v = *(const f32x4*)&Winb[gj], b1v = *(const f32x4*)&Winb[gj + 4];
  f32x4 v0 = s0 * inv_sigma + b0v, v1 = s1 * inv_sigma + b1v;
  *(f32x4*)&xp[base] = v0; *(f32x4*)&xp[base + 4] = v1;
  half8 hz = (half8){};
  *(half8*)&h16a[base] = hz;
}

// ===== persistent fused 90-layer kernel =====================================
// grid 256 WG x 512 thr; WG (rb=blk>>5, cb=blk&31) owns C tile [32 x 64].
// 8 waves, each owns K-window of 256 (K-split 8), frag grid m2 x n4.
// B (W) read via normal 16B loads -> XCD-L2 resident (cb%8 == blk%8 pins XCD).
// h read/written via agent-scope relaxed atomics (coherent at L3; no
// buffer_inv in the loop so W's L2 residency survives).
// Inter-layer: per-rb-group (32 WGs) release counter + relaxed spin.
__global__ void __launch_bounds__(512, 2)
k_persist(const h16* __restrict__ w16all, const float* __restrict__ b0,
          const float* __restrict__ b1, const float* __restrict__ b2,
          const float* __restrict__ xp, h16* hA, h16* hB,
          int* __restrict__ cnt) {
  __shared__ float red[8][8][64][4];   // [wave][frag][lidx(swizzled)][reg] 64 KB
  const int blk = blockIdx.x;
  const int rb = blk >> 5, cb = blk & 31;
  const int tid = threadIdx.x;
  const int w = tid >> 6, lane = tid & 63;
  const int mr = lane & 15, q = lane >> 4;
  // epilogue mapping: thread owns col ec, rows erq*4 .. erq*4+3
  const int ec = tid & 63, erq = tid >> 6;
  const int fn_e = ec >> 4, mr_e = ec & 15, fm_e = erq >> 2, q_e = erq & 3;
  const int lidx_e = q_e * 16 + ((mr_e + 4 * fn_e) & 15);
  const int fidx_e = fm_e * 4 + fn_e;

  const long ebase = (long)(rb * 32 + erq * 4) * 2048 + cb * 64 + ec;
  float xpv[4], h32[4];
#pragma unroll
  for (int i = 0; i < 4; ++i) { xpv[i] = xp[ebase + i * 2048]; h32[i] = 0.f; }
  const float bv0 = b0[cb * 64 + ec], bv1 = b1[cb * 64 + ec], bv2 = b2[cb * 64 + ec];

  const long aoff = (long)(rb * 32 + mr) * 2048 + w * 256 + q * 8;  // h16 elems
  const long woff = (long)(cb * 64 + mr) * 2048 + w * 256 + q * 8;
  h16* const hbufs[2] = {hA, hB};
  int* const flag = &cnt[rb * 32];

  union HL { u64 d[2]; half8 h; };
  union HS { h16 f; unsigned short s; };

  for (int l = 0; l < 90; ++l) {
    const h16* __restrict__ hin = hbufs[l & 1];
    h16* __restrict__ hout = hbufs[(l + 1) & 1];
    const h16* __restrict__ Wl = w16all + (long)(l % 3) * 4194304;

    f32x4 acc[2][4];
#pragma unroll
    for (int a = 0; a < 2; ++a)
#pragma unroll
      for (int c = 0; c < 4; ++c) acc[a][c] = (f32x4){0.f, 0.f, 0.f, 0.f};

    const u64* a0p = (const u64*)hin + (aoff >> 2);
    const u64* a1p = a0p + 8192;             // +16 rows * 2048 /4
    const h16* wp = Wl + woff;
#pragma unroll
    for (int ks = 0; ks < 8; ++ks) {
      const int o = ks * 8;                  // u64 units (32 h16)
      HL A0, A1;
      A0.d[0] = __hip_atomic_load(a0p + o,     __ATOMIC_RELAXED, __HIP_MEMORY_SCOPE_AGENT);
      A0.d[1] = __hip_atomic_load(a0p + o + 1, __ATOMIC_RELAXED, __HIP_MEMORY_SCOPE_AGENT);
      A1.d[0] = __hip_atomic_load(a1p + o,     __ATOMIC_RELAXED, __HIP_MEMORY_SCOPE_AGENT);
      A1.d[1] = __hip_atomic_load(a1p + o + 1, __ATOMIC_RELAXED, __HIP_MEMORY_SCOPE_AGENT);
#pragma unroll
      for (int fn = 0; fn < 4; ++fn) {
        half8 bv = *(const half8*)(wp + fn * 32768 + ks * 32);
        acc[0][fn] = __builtin_amdgcn_mfma_f32_16x16x32_f16(A0.h, bv, acc[0][fn], 0, 0, 0);
        acc[1][fn] = __builtin_amdgcn_mfma_f32_16x16x32_f16(A1.h, bv, acc[1][fn], 0, 0, 0);
      }
    }

    // K-reduction via swizzled LDS (conflict-free write & read)
#pragma unroll
    for (int fm = 0; fm < 2; ++fm)
#pragma unroll
      for (int fn = 0; fn < 4; ++fn)
        *(f32x4*)&red[w][fm * 4 + fn][q * 16 + ((mr + 4 * fn) & 15)][0] = acc[fm][fn];
    __syncthreads();

    f32x4 s = (f32x4){0.f, 0.f, 0.f, 0.f};
#pragma unroll
    for (int ww = 0; ww < 8; ++ww) s += *(const f32x4*)&red[ww][fidx_e][lidx_e][0];

    const int lm = l - (l / 3) * 3;
    const float bl_ = (lm == 0) ? bv0 : ((lm == 1) ? bv1 : bv2);
#pragma unroll
    for (int i = 0; i < 4; ++i) {
      const float z = xpv[i] + s[i] + bl_;
      h32[i] = 0.5f * h32[i] + 0.5f * fast_tanh(z);
      HS hs; hs.f = (h16)h32[i];
      __hip_atomic_store((unsigned short*)(hout + ebase + i * 2048), hs.s,
                         __ATOMIC_RELAXED, __HIP_MEMORY_SCOPE_AGENT);
    }
    __syncthreads();   // all stores drained (vmcnt(0) before s_barrier), red reads done

    if (tid == 0) {
      __hip_atomic_fetch_add(flag, 1, __ATOMIC_RELEASE, __HIP_MEMORY_SCOPE_AGENT);
      const int target = 32 * (l + 1);
      while (__hip_atomic_load(flag, __ATOMIC_RELAXED, __HIP_MEMORY_SCOPE_AGENT) < target)
        __builtin_amdgcn_s_sleep(1);
    }
    __syncthreads();
    asm volatile("" ::: "memory");
  }
}

// ===== head: out = h @ head_w^T + head_b ====================================
__global__ void __launch_bounds__(256)
k_head(const h16* __restrict__ hf, const h16* __restrict__ hw16,
       const float* __restrict__ hb, float* __restrict__ out) {
  __shared__ SmemGemm sm;
  const int rb = blockIdx.x >> 4, cb = blockIdx.x & 15;
  const int wave = threadIdx.x >> 6, lane = threadIdx.x & 63;
  gemm_core<2048>(sm, hf + rb * 32 * 2048, hw16 + (long)cb * 64 * 2048, wave, lane);
  const int e = threadIdx.x * 8;
  const int gi = rb * 32 + (e >> 6), gj = cb * 64 + (e & 63);
  f32x4 s0 = *(const f32x4*)&sm.red[0][e], s1 = *(const f32x4*)&sm.red[0][e + 4];
#pragma unroll
  for (int w = 1; w < 4; ++w) {
    s0 += *(const f32x4*)&sm.red[w][e];
    s1 += *(const f32x4*)&sm.red[w][e + 4];
  }
#pragma unroll
  for (int i = 0; i < 4; ++i) {
    int j0 = gj + i;
    if (j0 < 1000) out[(long)gi * 1000 + j0] = s0[i] + hb[j0];
    int j1 = gj + 4 + i;
    if (j1 < 1000) out[(long)gi * 1000 + j1] = s1[i] + hb[j1];
  }
}

// ===== workspace layout (bytes) =============================================
#define OFF_W16   0L          // 3 x 2048x2048 fp16 = 25165824
#define OFF_WI16  25165824L   // 2048x1024 fp16     =  4194304
#define OFF_X16   29360128L   // 256x1024 fp16      =   524288
#define OFF_HW16  29884416L   // 1024x2048 fp16     =  4194304
#define OFF_XP    34078720L   // 256x2048 fp32      =  2097152
#define OFF_H16A  36175872L   // 256x2048 fp16      =  1048576
#define OFF_H16B  37224448L   //                    =  1048576
#define OFF_T     38273024L   // 1024 fp32          =     4096
#define OFF_S     38277120L   // s1, s2             =      256
#define OFF_CNT   38277376L   // 256 ints           =     1024

extern "C" void kernel_launch(void* const* d_in, const int* in_sizes, int n_in,
                              void* d_out, int out_size, void* d_ws, size_t ws_size,
                              hipStream_t stream) {
  const float* x     = (const float*)d_in[0];
  const float* Win_w = (const float*)d_in[1];
  const float* Win_b = (const float*)d_in[2];
  const float* u     = (const float*)d_in[3];
  const float* W0    = (const float*)d_in[4];
  const float* b0    = (const float*)d_in[5];
  const float* W1    = (const float*)d_in[6];
  const float* b1    = (const float*)d_in[7];
  const float* W2    = (const float*)d_in[8];
  const float* b2    = (const float*)d_in[9];
  const float* headw = (const float*)d_in[10];
  const float* headb = (const float*)d_in[11];

  char* ws = (char*)d_ws;
  h16*   w16  = (h16*)(ws + OFF_W16);
  h16*   wi16 = (h16*)(ws + OFF_WI16);
  h16*   x16  = (h16*)(ws + OFF_X16);
  h16*   hw16 = (h16*)(ws + OFF_HW16);
  float* xp   = (float*)(ws + OFF_XP);
  h16*   h16a = (h16*)(ws + OFF_H16A);
  h16*   h16b = (h16*)(ws + OFF_H16B);
  float* tbuf = (float*)(ws + OFF_T);
  float* sbuf = (float*)(ws + OFF_S);
  int*   cnt  = (int*)(ws + OFF_CNT);

  k_zero<<<1, 256, 0, stream>>>(tbuf, sbuf, cnt);
  k_cvt<<<8320, 256, 0, stream>>>(W0, W1, W2, Win_w, headw, x, w16, wi16, hw16, x16);
  k_prep1<<<32, 256, 0, stream>>>(Win_w, u, tbuf);
  k_norm<<<1, 256, 0, stream>>>(tbuf, sbuf);
  k_prep2<<<512, 256, 0, stream>>>(Win_w, tbuf, sbuf);
  k_xproj<<<256, 256, 0, stream>>>(x16, wi16, Win_b, sbuf, xp, h16a);
  k_persist<<<256, 512, 0, stream>>>(w16, b0, b1, b2, xp, h16a, h16b, cnt);
  k_head<<<128, 256, 0, stream>>>(h16a, hw16, headb, (float*)d_out);
}

// Round 4
// 1996.953 us; speedup vs baseline: 1.0709x; 1.0709x over previous
//
#include <hip/hip_runtime.h>
#include <hip/hip_fp16.h>
#include <math.h>

typedef _Float16 h16;
typedef __attribute__((ext_vector_type(8))) _Float16 half8;
typedef __attribute__((ext_vector_type(4))) float f32x4;

#define GLOAD_LDS16(gp, lp) __builtin_amdgcn_global_load_lds( \
    (const __attribute__((address_space(1))) void*)(gp),      \
    (__attribute__((address_space(3))) void*)(lp), 16, 0, 0)

// ===== LDS-staged gemm core (used by k_xproj / k_head only) =================
union SmemGemm {
  h16   buf[2][96 * 128];
  float red[4][2048];
};

__device__ __forceinline__ void stage_tile(SmemGemm& sm, int b,
                                           const h16* __restrict__ Ag,
                                           const h16* __restrict__ Bg,
                                           int kk, int kdim, int wave, int lane) {
  h16* As = sm.buf[b];
  h16* Bs = As + 32 * 128;
  const int kb = kk * 128;
#pragma unroll
  for (int i = 0; i < 2; ++i) {
    const int id = wave * 2 + i;
    const int chunk = id * 64 + lane;
    GLOAD_LDS16(Ag + (long)(chunk >> 4) * kdim + kb + (chunk & 15) * 8,
                As + id * 512);
  }
#pragma unroll
  for (int i = 0; i < 4; ++i) {
    const int id = wave * 4 + i;
    const int chunk = id * 64 + lane;
    GLOAD_LDS16(Bg + (long)(chunk >> 4) * kdim + kb + (chunk & 15) * 8,
                Bs + id * 512);
  }
}

template <int KDIM>
__device__ __forceinline__ void gemm_core(SmemGemm& sm,
                                          const h16* __restrict__ Ag,
                                          const h16* __restrict__ Bg,
                                          int wave, int lane) {
  f32x4 acc[2][4];
#pragma unroll
  for (int a = 0; a < 2; ++a)
#pragma unroll
    for (int c = 0; c < 4; ++c) acc[a][c] = (f32x4){0.f, 0.f, 0.f, 0.f};

  const int mr = lane & 15, q = lane >> 4;
  constexpr int NIT = KDIM / 128;
  stage_tile(sm, 0, Ag, Bg, 0, KDIM, wave, lane);
  for (int kk = 0; kk < NIT; ++kk) {
    __syncthreads();
    if (kk + 1 < NIT) stage_tile(sm, (kk + 1) & 1, Ag, Bg, kk + 1, KDIM, wave, lane);
    const h16* As = sm.buf[kk & 1];
    const h16* Bs = As + 32 * 128;
    const int ko = wave * 32 + q * 8;
    half8 a0 = *(const half8*)(As + mr * 128 + ko);
    half8 a1 = *(const half8*)(As + (mr + 16) * 128 + ko);
#pragma unroll
    for (int fc = 0; fc < 4; ++fc) {
      half8 bv = *(const half8*)(Bs + (fc * 16 + mr) * 128 + ko);
      acc[0][fc] = __builtin_amdgcn_mfma_f32_16x16x32_f16(a0, bv, acc[0][fc], 0, 0, 0);
      acc[1][fc] = __builtin_amdgcn_mfma_f32_16x16x32_f16(a1, bv, acc[1][fc], 0, 0, 0);
    }
  }
  __syncthreads();
#pragma unroll
  for (int fr = 0; fr < 2; ++fr)
#pragma unroll
    for (int fc = 0; fc < 4; ++fc)
#pragma unroll
      for (int r = 0; r < 4; ++r)
        sm.red[wave][(fr * 16 + q * 4 + r) * 64 + fc * 16 + mr] = acc[fr][fc][r];
  __syncthreads();
}

__device__ __forceinline__ float fast_tanh(float x) {
  float e = __expf(2.0f * fabsf(x));
  float t = 1.0f - 2.0f / (e + 1.0f);
  return copysignf(t, x);
}

// ===== prep: sigma = ||W t|| / ||t||, t = W^T u =============================
__global__ void k_zero(float* t, float* sbuf, int* cnt) {
  const int i = threadIdx.x;
  for (int k = i; k < 1024; k += 256) t[k] = 0.f;
  if (i < 2) sbuf[i] = 0.f;
  cnt[i] = 0;
}

__global__ void __launch_bounds__(256)
k_prep1(const float* __restrict__ Win, const float* __restrict__ u,
        float* __restrict__ t) {
  const int k4 = threadIdx.x * 4;
  const int j0 = blockIdx.x * 64;
  f32x4 acc = (f32x4){0.f, 0.f, 0.f, 0.f};
  for (int j = j0; j < j0 + 64; ++j) {
    f32x4 wv = *(const f32x4*)&Win[(long)j * 1024 + k4];
    acc += wv * u[j];
  }
#pragma unroll
  for (int i = 0; i < 4; ++i) atomicAdd(&t[k4 + i], acc[i]);
}

__global__ void __launch_bounds__(256)
k_norm(const float* __restrict__ t, float* __restrict__ sbuf) {
  f32x4 v = *(const f32x4*)&t[threadIdx.x * 4];
  float s = v[0] * v[0] + v[1] * v[1] + v[2] * v[2] + v[3] * v[3];
#pragma unroll
  for (int off = 32; off > 0; off >>= 1) s += __shfl_down(s, off);
  if ((threadIdx.x & 63) == 0) atomicAdd(&sbuf[0], s);  // s1 = ||t||^2
}

__global__ void __launch_bounds__(256)
k_prep2(const float* __restrict__ Win, const float* __restrict__ t,
        float* __restrict__ sbuf) {
  const int row = blockIdx.x * 4 + (threadIdx.x >> 6);
  const int lane = threadIdx.x & 63;
  float acc = 0.f;
  for (int kk = lane; kk < 1024; kk += 64)
    acc = fmaf(Win[row * 1024 + kk], t[kk], acc);
#pragma unroll
  for (int off = 32; off > 0; off >>= 1) acc += __shfl_down(acc, off);
  if (lane == 0) atomicAdd(&sbuf[1], acc * acc);        // s2 = ||W t||^2
}

// ===== fp32 -> fp16 conversions =============================================
__global__ void __launch_bounds__(256)
k_cvt(const float* __restrict__ W0, const float* __restrict__ W1,
      const float* __restrict__ W2, const float* __restrict__ Win,
      const float* __restrict__ Hw, const float* __restrict__ X,
      h16* __restrict__ w16, h16* __restrict__ wi16,
      h16* __restrict__ hw16, h16* __restrict__ x16) {
  const long e = (long)(blockIdx.x * 256 + threadIdx.x) * 8;
  const float* src; h16* dst;
  if (e < 4194304)       { src = W0 + e;              dst = w16 + e; }
  else if (e < 8388608)  { src = W1 + (e - 4194304);  dst = w16 + e; }
  else if (e < 12582912) { src = W2 + (e - 8388608);  dst = w16 + e; }
  else if (e < 14680064) { src = Win + (e - 12582912); dst = wi16 + (e - 12582912); }
  else if (e < 16728064) { src = Hw + (e - 14680064);  dst = hw16 + (e - 14680064); }
  else if (e < 16777216) {
    half8 z = (half8){};
    *(half8*)(hw16 + 2048000 + (e - 16728064)) = z;
    return;
  }
  else                   { src = X + (e - 16777216);   dst = x16 + (e - 16777216); }
  f32x4 f0 = *(const f32x4*)src, f1 = *(const f32x4*)(src + 4);
  half8 h;
#pragma unroll
  for (int i = 0; i < 4; ++i) { h[i] = (h16)f0[i]; h[i + 4] = (h16)f1[i]; }
  *(half8*)dst = h;
}

// ===== x_proj = (x @ Win^T)/sigma + Win_b; zero hbuf[0] =====================
__global__ void __launch_bounds__(256)
k_xproj(const h16* __restrict__ x16, const h16* __restrict__ wi16,
        const float* __restrict__ Winb, const float* __restrict__ sbuf,
        float* __restrict__ xp, h16* __restrict__ h16a) {
  __shared__ SmemGemm sm;
  const int rb = blockIdx.x >> 5, cb = blockIdx.x & 31;
  const int wave = threadIdx.x >> 6, lane = threadIdx.x & 63;
  gemm_core<1024>(sm, x16 + rb * 32 * 1024, wi16 + (long)cb * 64 * 1024, wave, lane);
  const float inv_sigma = sqrtf(sbuf[0] / sbuf[1]);
  const int e = threadIdx.x * 8;
  const int gi = rb * 32 + (e >> 6), gj = cb * 64 + (e & 63);
  const long base = (long)gi * 2048 + gj;
  f32x4 s0 = *(const f32x4*)&sm.red[0][e], s1 = *(const f32x4*)&sm.red[0][e + 4];
#pragma unroll
  for (int w = 1; w < 4; ++w) {
    s0 += *(const f32x4*)&sm.red[w][e];
    s1 += *(const f32x4*)&sm.red[w][e + 4];
  }
  f32x4 b0v = *(const f32x4*)&Winb[gj], b1v = *(const f32x4*)&Winb[gj + 4];
  f32x4 v0 = s0 * inv_sigma + b0v, v1 = s1 * inv_sigma + b1v;
  *(f32x4*)&xp[base] = v0; *(f32x4*)&xp[base + 4] = v1;
  half8 hz = (half8){};
  *(half8*)&h16a[base] = hz;
}

// ===== persistent fused 90-layer kernel =====================================
// grid 256 WG x 512 thr; WG (rb=blk>>5, cb=blk&31) owns C tile [32 x 64].
// 8 waves, each owns a K-window of 256 (K-split 8), frag grid m2 x n4.
// W: normal cached 16B loads; cb%8==blk%8 pins each W column-slice to one
//    XCD -> 3 MB/XCD working set stays L2-resident (never invalidated).
// h: producer stores normally; RELEASE fetch_add emits buffer_wbl2 (push to
//    L3); consumers read h with sc0+sc1 (L1/L2-bypass) 16B asm loads -> no
//    stale-line hazard, no L2 invalidate, one vmcnt(0) per layer.
// Inter-layer: per-rb-group (32 WGs) release counter + relaxed spin.
__global__ void __launch_bounds__(512, 2)
k_persist(const h16* __restrict__ w16all, const float* __restrict__ b0,
          const float* __restrict__ b1, const float* __restrict__ b2,
          const float* __restrict__ xp, h16* hA, h16* hB,
          int* __restrict__ cnt) {
  __shared__ float red[8][8][64][4];   // [wave][frag][lidx(swizzled)][reg] 64 KB
  const int blk = blockIdx.x;
  const int rb = blk >> 5, cb = blk & 31;
  const int tid = threadIdx.x;
  const int w = tid >> 6, lane = tid & 63;
  const int mr = lane & 15, q = lane >> 4;
  // epilogue mapping: thread owns col ec, rows erq*4 .. erq*4+3
  const int ec = tid & 63, erq = tid >> 6;
  const int fn_e = ec >> 4, mr_e = ec & 15, fm_e = erq >> 2, q_e = erq & 3;
  const int lidx_e = q_e * 16 + ((mr_e + 4 * fn_e) & 15);
  const int fidx_e = fm_e * 4 + fn_e;

  const long ebase = (long)(rb * 32 + erq * 4) * 2048 + cb * 64 + ec;
  float xpv[4], h32[4];
#pragma unroll
  for (int i = 0; i < 4; ++i) { xpv[i] = xp[ebase + i * 2048]; h32[i] = 0.f; }
  const float bv0 = b0[cb * 64 + ec], bv1 = b1[cb * 64 + ec], bv2 = b2[cb * 64 + ec];

  const long aoff = (long)(rb * 32 + mr) * 2048 + w * 256 + q * 8;  // h16 elems
  const long woff = (long)(cb * 64 + mr) * 2048 + w * 256 + q * 8;
  h16* const hbufs[2] = {hA, hB};
  int* const flag = &cnt[rb * 32];

  union HL { f32x4 f; half8 h; };

  for (int l = 0; l < 90; ++l) {
    const h16* __restrict__ hin = hbufs[l & 1];
    h16* __restrict__ hout = hbufs[(l + 1) & 1];
    const h16* __restrict__ Wl = w16all + (long)(l % 3) * 4194304;

    f32x4 acc[2][4];
#pragma unroll
    for (int a = 0; a < 2; ++a)
#pragma unroll
      for (int c = 0; c < 4; ++c) acc[a][c] = (f32x4){0.f, 0.f, 0.f, 0.f};

    const h16* a0p = hin + aoff;
    const h16* a1p = a0p + 32768;            // +16 rows * 2048
    const h16* wp = Wl + woff;

    // --- batched L2-bypass A loads (16B each), one waitcnt -----------------
    HL A0[8], A1[8];
#pragma unroll
    for (int ks = 0; ks < 8; ++ks) {
      asm volatile("global_load_dwordx4 %0, %1, off sc0 sc1"
                   : "=v"(A0[ks].f) : "v"(a0p + ks * 32));
      asm volatile("global_load_dwordx4 %0, %1, off sc0 sc1"
                   : "=v"(A1[ks].f) : "v"(a1p + ks * 32));
    }
    asm volatile("s_waitcnt vmcnt(0)"
                 : "+v"(A0[0].f), "+v"(A0[1].f), "+v"(A0[2].f), "+v"(A0[3].f),
                   "+v"(A0[4].f), "+v"(A0[5].f), "+v"(A0[6].f), "+v"(A0[7].f),
                   "+v"(A1[0].f), "+v"(A1[1].f), "+v"(A1[2].f), "+v"(A1[3].f),
                   "+v"(A1[4].f), "+v"(A1[5].f), "+v"(A1[6].f), "+v"(A1[7].f));

#pragma unroll
    for (int ks = 0; ks < 8; ++ks) {
#pragma unroll
      for (int fn = 0; fn < 4; ++fn) {
        half8 bv = *(const half8*)(wp + fn * 32768 + ks * 32);
        acc[0][fn] = __builtin_amdgcn_mfma_f32_16x16x32_f16(A0[ks].h, bv, acc[0][fn], 0, 0, 0);
        acc[1][fn] = __builtin_amdgcn_mfma_f32_16x16x32_f16(A1[ks].h, bv, acc[1][fn], 0, 0, 0);
      }
    }

    // K-reduction via swizzled LDS (conflict-free write & read)
#pragma unroll
    for (int fm = 0; fm < 2; ++fm)
#pragma unroll
      for (int fn = 0; fn < 4; ++fn)
        *(f32x4*)&red[w][fm * 4 + fn][q * 16 + ((mr + 4 * fn) & 15)][0] = acc[fm][fn];
    __syncthreads();

    f32x4 s = (f32x4){0.f, 0.f, 0.f, 0.f};
#pragma unroll
    for (int ww = 0; ww < 8; ++ww) s += *(const f32x4*)&red[ww][fidx_e][lidx_e][0];

    const int lm = l - (l / 3) * 3;
    const float bl_ = (lm == 0) ? bv0 : ((lm == 1) ? bv1 : bv2);
#pragma unroll
    for (int i = 0; i < 4; ++i) {
      const float z = xpv[i] + s[i] + bl_;
      h32[i] = 0.5f * h32[i] + 0.5f * fast_tanh(z);
      hout[ebase + i * 2048] = (h16)h32[i];
    }
    __syncthreads();   // drains each wave's stores to L2; red reads done

    if (tid == 0) {
      // RELEASE: compiler emits buffer_wbl2 + vmcnt drain before the add ->
      // this WG's h stores (already in L2) are pushed to L3 for sc1 readers.
      __hip_atomic_fetch_add(flag, 1, __ATOMIC_RELEASE, __HIP_MEMORY_SCOPE_AGENT);
      const int target = 32 * (l + 1);
      while (__hip_atomic_load(flag, __ATOMIC_RELAXED, __HIP_MEMORY_SCOPE_AGENT) < target)
        __builtin_amdgcn_s_sleep(1);
    }
    __syncthreads();
    asm volatile("" ::: "memory");
  }
}

// ===== head: out = h @ head_w^T + head_b ====================================
__global__ void __launch_bounds__(256)
k_head(const h16* __restrict__ hf, const h16* __restrict__ hw16,
       const float* __restrict__ hb, float* __restrict__ out) {
  __shared__ SmemGemm sm;
  const int rb = blockIdx.x >> 4, cb = blockIdx.x & 15;
  const int wave = threadIdx.x >> 6, lane = threadIdx.x & 63;
  gemm_core<2048>(sm, hf + rb * 32 * 2048, hw16 + (long)cb * 64 * 2048, wave, lane);
  const int e = threadIdx.x * 8;
  const int gi = rb * 32 + (e >> 6), gj = cb * 64 + (e & 63);
  f32x4 s0 = *(const f32x4*)&sm.red[0][e], s1 = *(const f32x4*)&sm.red[0][e + 4];
#pragma unroll
  for (int w = 1; w < 4; ++w) {
    s0 += *(const f32x4*)&sm.red[w][e];
    s1 += *(const f32x4*)&sm.red[w][e + 4];
  }
#pragma unroll
  for (int i = 0; i < 4; ++i) {
    int j0 = gj + i;
    if (j0 < 1000) out[(long)gi * 1000 + j0] = s0[i] + hb[j0];
    int j1 = gj + 4 + i;
    if (j1 < 1000) out[(long)gi * 1000 + j1] = s1[i] + hb[j1];
  }
}

// ===== workspace layout (bytes) =============================================
#define OFF_W16   0L          // 3 x 2048x2048 fp16 = 25165824
#define OFF_WI16  25165824L   // 2048x1024 fp16     =  4194304
#define OFF_X16   29360128L   // 256x1024 fp16      =   524288
#define OFF_HW16  29884416L   // 1024x2048 fp16     =  4194304
#define OFF_XP    34078720L   // 256x2048 fp32      =  2097152
#define OFF_H16A  36175872L   // 256x2048 fp16      =  1048576
#define OFF_H16B  37224448L   //                    =  1048576
#define OFF_T     38273024L   // 1024 fp32          =     4096
#define OFF_S     38277120L   // s1, s2             =      256
#define OFF_CNT   38277376L   // 256 ints           =     1024

extern "C" void kernel_launch(void* const* d_in, const int* in_sizes, int n_in,
                              void* d_out, int out_size, void* d_ws, size_t ws_size,
                              hipStream_t stream) {
  const float* x     = (const float*)d_in[0];
  const float* Win_w = (const float*)d_in[1];
  const float* Win_b = (const float*)d_in[2];
  const float* u     = (const float*)d_in[3];
  const float* W0    = (const float*)d_in[4];
  const float* b0    = (const float*)d_in[5];
  const float* W1    = (const float*)d_in[6];
  const float* b1    = (const float*)d_in[7];
  const float* W2    = (const float*)d_in[8];
  const float* b2    = (const float*)d_in[9];
  const float* headw = (const float*)d_in[10];
  const float* headb = (const float*)d_in[11];

  char* ws = (char*)d_ws;
  h16*   w16  = (h16*)(ws + OFF_W16);
  h16*   wi16 = (h16*)(ws + OFF_WI16);
  h16*   x16  = (h16*)(ws + OFF_X16);
  h16*   hw16 = (h16*)(ws + OFF_HW16);
  float* xp   = (float*)(ws + OFF_XP);
  h16*   h16a = (h16*)(ws + OFF_H16A);
  h16*   h16b = (h16*)(ws + OFF_H16B);
  float* tbuf = (float*)(ws + OFF_T);
  float* sbuf = (float*)(ws + OFF_S);
  int*   cnt  = (int*)(ws + OFF_CNT);

  k_zero<<<1, 256, 0, stream>>>(tbuf, sbuf, cnt);
  k_cvt<<<8320, 256, 0, stream>>>(W0, W1, W2, Win_w, headw, x, w16, wi16, hw16, x16);
  k_prep1<<<32, 256, 0, stream>>>(Win_w, u, tbuf);
  k_norm<<<1, 256, 0, stream>>>(tbuf, sbuf);
  k_prep2<<<512, 256, 0, stream>>>(Win_w, tbuf, sbuf);
  k_xproj<<<256, 256, 0, stream>>>(x16, wi16, Win_b, sbuf, xp, h16a);
  k_persist<<<256, 512, 0, stream>>>(w16, b0, b1, b2, xp, h16a, h16b, cnt);
  k_head<<<128, 256, 0, stream>>>(h16a, hw16, headb, (float*)d_out);
}

// Round 5
// 1664.350 us; speedup vs baseline: 1.2849x; 1.1998x over previous
//
#include <hip/hip_runtime.h>
#include <hip/hip_fp16.h>
#include <math.h>

typedef _Float16 h16;
typedef __attribute__((ext_vector_type(8))) _Float16 half8;
typedef __attribute__((ext_vector_type(4))) float f32x4;

#define GLOAD_LDS16(gp, lp) __builtin_amdgcn_global_load_lds( \
    (const __attribute__((address_space(1))) void*)(gp),      \
    (__attribute__((address_space(3))) void*)(lp), 16, 0, 0)

// ===== LDS-staged gemm core (used by k_xproj / k_head only) =================
union SmemGemm {
  h16   buf[2][96 * 128];
  float red[4][2048];
};

__device__ __forceinline__ void stage_tile(SmemGemm& sm, int b,
                                           const h16* __restrict__ Ag,
                                           const h16* __restrict__ Bg,
                                           int kk, int kdim, int wave, int lane) {
  h16* As = sm.buf[b];
  h16* Bs = As + 32 * 128;
  const int kb = kk * 128;
#pragma unroll
  for (int i = 0; i < 2; ++i) {
    const int id = wave * 2 + i;
    const int chunk = id * 64 + lane;
    GLOAD_LDS16(Ag + (long)(chunk >> 4) * kdim + kb + (chunk & 15) * 8,
                As + id * 512);
  }
#pragma unroll
  for (int i = 0; i < 4; ++i) {
    const int id = wave * 4 + i;
    const int chunk = id * 64 + lane;
    GLOAD_LDS16(Bg + (long)(chunk >> 4) * kdim + kb + (chunk & 15) * 8,
                Bs + id * 512);
  }
}

template <int KDIM>
__device__ __forceinline__ void gemm_core(SmemGemm& sm,
                                          const h16* __restrict__ Ag,
                                          const h16* __restrict__ Bg,
                                          int wave, int lane) {
  f32x4 acc[2][4];
#pragma unroll
  for (int a = 0; a < 2; ++a)
#pragma unroll
    for (int c = 0; c < 4; ++c) acc[a][c] = (f32x4){0.f, 0.f, 0.f, 0.f};

  const int mr = lane & 15, q = lane >> 4;
  constexpr int NIT = KDIM / 128;
  stage_tile(sm, 0, Ag, Bg, 0, KDIM, wave, lane);
  for (int kk = 0; kk < NIT; ++kk) {
    __syncthreads();
    if (kk + 1 < NIT) stage_tile(sm, (kk + 1) & 1, Ag, Bg, kk + 1, KDIM, wave, lane);
    const h16* As = sm.buf[kk & 1];
    const h16* Bs = As + 32 * 128;
    const int ko = wave * 32 + q * 8;
    half8 a0 = *(const half8*)(As + mr * 128 + ko);
    half8 a1 = *(const half8*)(As + (mr + 16) * 128 + ko);
#pragma unroll
    for (int fc = 0; fc < 4; ++fc) {
      half8 bv = *(const half8*)(Bs + (fc * 16 + mr) * 128 + ko);
      acc[0][fc] = __builtin_amdgcn_mfma_f32_16x16x32_f16(a0, bv, acc[0][fc], 0, 0, 0);
      acc[1][fc] = __builtin_amdgcn_mfma_f32_16x16x32_f16(a1, bv, acc[1][fc], 0, 0, 0);
    }
  }
  __syncthreads();
#pragma unroll
  for (int fr = 0; fr < 2; ++fr)
#pragma unroll
    for (int fc = 0; fc < 4; ++fc)
#pragma unroll
      for (int r = 0; r < 4; ++r)
        sm.red[wave][(fr * 16 + q * 4 + r) * 64 + fc * 16 + mr] = acc[fr][fc][r];
  __syncthreads();
}

__device__ __forceinline__ float fast_tanh(float x) {
  float e = __expf(2.0f * fabsf(x));
  float t = 1.0f - 2.0f / (e + 1.0f);
  return copysignf(t, x);
}

// ===== prep: sigma = ||W t|| / ||t||, t = W^T u =============================
__global__ void k_zero(float* t, float* sbuf, int* cnt) {
  const int i = threadIdx.x;
  for (int k = i; k < 1024; k += 256) t[k] = 0.f;
  if (i < 2) sbuf[i] = 0.f;
  cnt[i] = 0;
}

__global__ void __launch_bounds__(256)
k_prep1(const float* __restrict__ Win, const float* __restrict__ u,
        float* __restrict__ t) {
  const int k4 = threadIdx.x * 4;
  const int j0 = blockIdx.x * 64;
  f32x4 acc = (f32x4){0.f, 0.f, 0.f, 0.f};
  for (int j = j0; j < j0 + 64; ++j) {
    f32x4 wv = *(const f32x4*)&Win[(long)j * 1024 + k4];
    acc += wv * u[j];
  }
#pragma unroll
  for (int i = 0; i < 4; ++i) atomicAdd(&t[k4 + i], acc[i]);
}

__global__ void __launch_bounds__(256)
k_norm(const float* __restrict__ t, float* __restrict__ sbuf) {
  f32x4 v = *(const f32x4*)&t[threadIdx.x * 4];
  float s = v[0] * v[0] + v[1] * v[1] + v[2] * v[2] + v[3] * v[3];
#pragma unroll
  for (int off = 32; off > 0; off >>= 1) s += __shfl_down(s, off);
  if ((threadIdx.x & 63) == 0) atomicAdd(&sbuf[0], s);  // s1 = ||t||^2
}

__global__ void __launch_bounds__(256)
k_prep2(const float* __restrict__ Win, const float* __restrict__ t,
        float* __restrict__ sbuf) {
  const int row = blockIdx.x * 4 + (threadIdx.x >> 6);
  const int lane = threadIdx.x & 63;
  float acc = 0.f;
  for (int kk = lane; kk < 1024; kk += 64)
    acc = fmaf(Win[row * 1024 + kk], t[kk], acc);
#pragma unroll
  for (int off = 32; off > 0; off >>= 1) acc += __shfl_down(acc, off);
  if (lane == 0) atomicAdd(&sbuf[1], acc * acc);        // s2 = ||W t||^2
}

// ===== fp32 -> fp16 conversions =============================================
__global__ void __launch_bounds__(256)
k_cvt(const float* __restrict__ W0, const float* __restrict__ W1,
      const float* __restrict__ W2, const float* __restrict__ Win,
      const float* __restrict__ Hw, const float* __restrict__ X,
      h16* __restrict__ w16, h16* __restrict__ wi16,
      h16* __restrict__ hw16, h16* __restrict__ x16) {
  const long e = (long)(blockIdx.x * 256 + threadIdx.x) * 8;
  const float* src; h16* dst;
  if (e < 4194304)       { src = W0 + e;              dst = w16 + e; }
  else if (e < 8388608)  { src = W1 + (e - 4194304);  dst = w16 + e; }
  else if (e < 12582912) { src = W2 + (e - 8388608);  dst = w16 + e; }
  else if (e < 14680064) { src = Win + (e - 12582912); dst = wi16 + (e - 12582912); }
  else if (e < 16728064) { src = Hw + (e - 14680064);  dst = hw16 + (e - 14680064); }
  else if (e < 16777216) {
    half8 z = (half8){};
    *(half8*)(hw16 + 2048000 + (e - 16728064)) = z;
    return;
  }
  else                   { src = X + (e - 16777216);   dst = x16 + (e - 16777216); }
  f32x4 f0 = *(const f32x4*)src, f1 = *(const f32x4*)(src + 4);
  half8 h;
#pragma unroll
  for (int i = 0; i < 4; ++i) { h[i] = (h16)f0[i]; h[i + 4] = (h16)f1[i]; }
  *(half8*)dst = h;
}

// ===== x_proj = (x @ Win^T)/sigma + Win_b; zero hbuf[0] =====================
__global__ void __launch_bounds__(256)
k_xproj(const h16* __restrict__ x16, const h16* __restrict__ wi16,
        const float* __restrict__ Winb, const float* __restrict__ sbuf,
        float* __restrict__ xp, h16* __restrict__ h16a) {
  __shared__ SmemGemm sm;
  const int rb = blockIdx.x >> 5, cb = blockIdx.x & 31;
  const int wave = threadIdx.x >> 6, lane = threadIdx.x & 63;
  gemm_core<1024>(sm, x16 + rb * 32 * 1024, wi16 + (long)cb * 64 * 1024, wave, lane);
  const float inv_sigma = sqrtf(sbuf[0] / sbuf[1]);
  const int e = threadIdx.x * 8;
  const int gi = rb * 32 + (e >> 6), gj = cb * 64 + (e & 63);
  const long base = (long)gi * 2048 + gj;
  f32x4 s0 = *(const f32x4*)&sm.red[0][e], s1 = *(const f32x4*)&sm.red[0][e + 4];
#pragma unroll
  for (int w = 1; w < 4; ++w) {
    s0 += *(const f32x4*)&sm.red[w][e];
    s1 += *(const f32x4*)&sm.red[w][e + 4];
  }
  f32x4 b0v = *(const f32x4*)&Winb[gj], b1v = *(const f32x4*)&Winb[gj + 4];
  f32x4 v0 = s0 * inv_sigma + b0v, v1 = s1 * inv_sigma + b1v;
  *(f32x4*)&xp[base] = v0; *(f32x4*)&xp[base + 4] = v1;
  half8 hz = (half8){};
  *(half8*)&h16a[base] = hz;
}

// ===== persistent fused 90-layer kernel =====================================
// grid 256 WG x 512 thr; WG (rb=blk>>5, cb=blk&31) owns C tile [32 x 64].
// 8 waves, each owns a K-window of 256 (K-split 8), frag grid m2 x n4.
// W: normal cached 16B loads; cb%8==blk%8 pins each W column-slice to one
//    XCD. Per-XCD L2 working set = 3 MB W only (h reads AND writes bypass
//    L2 via sc0 sc1) -> W stays L2-resident across all 90 layers.
// h: epilogue stores are sc0 sc1 (write-through to L3, no L2 dirty lines);
//    consumers read h with sc0 sc1 16B asm loads from L3.
// Inter-layer: per-rb-group (32 WGs) release counter + relaxed spin.
__global__ void __launch_bounds__(512, 2)
k_persist(const h16* __restrict__ w16all, const float* __restrict__ b0,
          const float* __restrict__ b1, const float* __restrict__ b2,
          const float* __restrict__ xp, h16* hA, h16* hB,
          int* __restrict__ cnt) {
  __shared__ float red[8][8][64][4];   // [wave][frag][lidx(swizzled)][reg] 64 KB
  const int blk = blockIdx.x;
  const int rb = blk >> 5, cb = blk & 31;
  const int tid = threadIdx.x;
  const int w = tid >> 6, lane = tid & 63;
  const int mr = lane & 15, q = lane >> 4;
  // epilogue mapping: thread owns col ec, rows erq*4 .. erq*4+3
  const int ec = tid & 63, erq = tid >> 6;
  const int fn_e = ec >> 4, mr_e = ec & 15, fm_e = erq >> 2, q_e = erq & 3;
  const int lidx_e = q_e * 16 + ((mr_e + 4 * fn_e) & 15);
  const int fidx_e = fm_e * 4 + fn_e;

  const long ebase = (long)(rb * 32 + erq * 4) * 2048 + cb * 64 + ec;
  float xpv[4], h32[4];
#pragma unroll
  for (int i = 0; i < 4; ++i) { xpv[i] = xp[ebase + i * 2048]; h32[i] = 0.f; }
  const float bv0 = b0[cb * 64 + ec], bv1 = b1[cb * 64 + ec], bv2 = b2[cb * 64 + ec];

  const long aoff = (long)(rb * 32 + mr) * 2048 + w * 256 + q * 8;  // h16 elems
  const long woff = (long)(cb * 64 + mr) * 2048 + w * 256 + q * 8;
  h16* const hbufs[2] = {hA, hB};
  int* const flag = &cnt[rb * 32];

  union HL { f32x4 f; half8 h; };
  union HS { h16 f; unsigned short s; };

  for (int l = 0; l < 90; ++l) {
    const h16* __restrict__ hin = hbufs[l & 1];
    h16* __restrict__ hout = hbufs[(l + 1) & 1];
    const h16* __restrict__ Wl = w16all + (long)(l % 3) * 4194304;

    f32x4 acc[2][4];
#pragma unroll
    for (int a = 0; a < 2; ++a)
#pragma unroll
      for (int c = 0; c < 4; ++c) acc[a][c] = (f32x4){0.f, 0.f, 0.f, 0.f};

    const h16* a0p = hin + aoff;
    const h16* a1p = a0p + 32768;            // +16 rows * 2048
    const h16* wp = Wl + woff;

    // --- batched L2-bypass A loads (16B each), one waitcnt -----------------
    HL A0[8], A1[8];
#pragma unroll
    for (int ks = 0; ks < 8; ++ks) {
      asm volatile("global_load_dwordx4 %0, %1, off sc0 sc1"
                   : "=v"(A0[ks].f) : "v"(a0p + ks * 32));
      asm volatile("global_load_dwordx4 %0, %1, off sc0 sc1"
                   : "=v"(A1[ks].f) : "v"(a1p + ks * 32));
    }
    asm volatile("s_waitcnt vmcnt(0)"
                 : "+v"(A0[0].f), "+v"(A0[1].f), "+v"(A0[2].f), "+v"(A0[3].f),
                   "+v"(A0[4].f), "+v"(A0[5].f), "+v"(A0[6].f), "+v"(A0[7].f),
                   "+v"(A1[0].f), "+v"(A1[1].f), "+v"(A1[2].f), "+v"(A1[3].f),
                   "+v"(A1[4].f), "+v"(A1[5].f), "+v"(A1[6].f), "+v"(A1[7].f));

#pragma unroll
    for (int ks = 0; ks < 8; ++ks) {
#pragma unroll
      for (int fn = 0; fn < 4; ++fn) {
        half8 bv = *(const half8*)(wp + fn * 32768 + ks * 32);
        acc[0][fn] = __builtin_amdgcn_mfma_f32_16x16x32_f16(A0[ks].h, bv, acc[0][fn], 0, 0, 0);
        acc[1][fn] = __builtin_amdgcn_mfma_f32_16x16x32_f16(A1[ks].h, bv, acc[1][fn], 0, 0, 0);
      }
    }

    // K-reduction via swizzled LDS (conflict-free write & read)
#pragma unroll
    for (int fm = 0; fm < 2; ++fm)
#pragma unroll
      for (int fn = 0; fn < 4; ++fn)
        *(f32x4*)&red[w][fm * 4 + fn][q * 16 + ((mr + 4 * fn) & 15)][0] = acc[fm][fn];
    __syncthreads();

    f32x4 s = (f32x4){0.f, 0.f, 0.f, 0.f};
#pragma unroll
    for (int ww = 0; ww < 8; ++ww) s += *(const f32x4*)&red[ww][fidx_e][lidx_e][0];

    const int lm = l - (l / 3) * 3;
    const float bl_ = (lm == 0) ? bv0 : ((lm == 1) ? bv1 : bv2);
#pragma unroll
    for (int i = 0; i < 4; ++i) {
      const float z = xpv[i] + s[i] + bl_;
      h32[i] = 0.5f * h32[i] + 0.5f * fast_tanh(z);
      HS hs; hs.f = (h16)h32[i];
      // write-through to L3 (no L2 allocate): keeps W L2-resident
      asm volatile("global_store_short %0, %1, off sc0 sc1"
                   :: "v"(hout + ebase + (long)i * 2048), "v"((unsigned)hs.s)
                   : "memory");
    }
    __syncthreads();   // drains each wave's stores (vmcnt(0)); red reads done

    if (tid == 0) {
      // RELEASE: wbl2 now cheap (no dirty h lines); pushes visibility to L3.
      __hip_atomic_fetch_add(flag, 1, __ATOMIC_RELEASE, __HIP_MEMORY_SCOPE_AGENT);
      const int target = 32 * (l + 1);
      while (__hip_atomic_load(flag, __ATOMIC_RELAXED, __HIP_MEMORY_SCOPE_AGENT) < target)
        __builtin_amdgcn_s_sleep(1);
    }
    __syncthreads();
    asm volatile("" ::: "memory");
  }
}

// ===== head: out = h @ head_w^T + head_b ====================================
__global__ void __launch_bounds__(256)
k_head(const h16* __restrict__ hf, const h16* __restrict__ hw16,
       const float* __restrict__ hb, float* __restrict__ out) {
  __shared__ SmemGemm sm;
  const int rb = blockIdx.x >> 4, cb = blockIdx.x & 15;
  const int wave = threadIdx.x >> 6, lane = threadIdx.x & 63;
  gemm_core<2048>(sm, hf + rb * 32 * 2048, hw16 + (long)cb * 64 * 2048, wave, lane);
  const int e = threadIdx.x * 8;
  const int gi = rb * 32 + (e >> 6), gj = cb * 64 + (e & 63);
  f32x4 s0 = *(const f32x4*)&sm.red[0][e], s1 = *(const f32x4*)&sm.red[0][e + 4];
#pragma unroll
  for (int w = 1; w < 4; ++w) {
    s0 += *(const f32x4*)&sm.red[w][e];
    s1 += *(const f32x4*)&sm.red[w][e + 4];
  }
#pragma unroll
  for (int i = 0; i < 4; ++i) {
    int j0 = gj + i;
    if (j0 < 1000) out[(long)gi * 1000 + j0] = s0[i] + hb[j0];
    int j1 = gj + 4 + i;
    if (j1 < 1000) out[(long)gi * 1000 + j1] = s1[i] + hb[j1];
  }
}

// ===== workspace layout (bytes) =============================================
#define OFF_W16   0L          // 3 x 2048x2048 fp16 = 25165824
#define OFF_WI16  25165824L   // 2048x1024 fp16     =  4194304
#define OFF_X16   29360128L   // 256x1024 fp16      =   524288
#define OFF_HW16  29884416L   // 1024x2048 fp16     =  4194304
#define OFF_XP    34078720L   // 256x2048 fp32      =  2097152
#define OFF_H16A  36175872L   // 256x2048 fp16      =  1048576
#define OFF_H16B  37224448L   //                    =  1048576
#define OFF_T     38273024L   // 1024 fp32          =     4096
#define OFF_S     38277120L   // s1, s2             =      256
#define OFF_CNT   38277376L   // 256 ints           =     1024

extern "C" void kernel_launch(void* const* d_in, const int* in_sizes, int n_in,
                              void* d_out, int out_size, void* d_ws, size_t ws_size,
                              hipStream_t stream) {
  const float* x     = (const float*)d_in[0];
  const float* Win_w = (const float*)d_in[1];
  const float* Win_b = (const float*)d_in[2];
  const float* u     = (const float*)d_in[3];
  const float* W0    = (const float*)d_in[4];
  const float* b0    = (const float*)d_in[5];
  const float* W1    = (const float*)d_in[6];
  const float* b1    = (const float*)d_in[7];
  const float* W2    = (const float*)d_in[8];
  const float* b2    = (const float*)d_in[9];
  const float* headw = (const float*)d_in[10];
  const float* headb = (const float*)d_in[11];

  char* ws = (char*)d_ws;
  h16*   w16  = (h16*)(ws + OFF_W16);
  h16*   wi16 = (h16*)(ws + OFF_WI16);
  h16*   x16  = (h16*)(ws + OFF_X16);
  h16*   hw16 = (h16*)(ws + OFF_HW16);
  float* xp   = (float*)(ws + OFF_XP);
  h16*   h16a = (h16*)(ws + OFF_H16A);
  h16*   h16b = (h16*)(ws + OFF_H16B);
  float* tbuf = (float*)(ws + OFF_T);
  float* sbuf = (float*)(ws + OFF_S);
  int*   cnt  = (int*)(ws + OFF_CNT);

  k_zero<<<1, 256, 0, stream>>>(tbuf, sbuf, cnt);
  k_cvt<<<8320, 256, 0, stream>>>(W0, W1, W2, Win_w, headw, x, w16, wi16, hw16, x16);
  k_prep1<<<32, 256, 0, stream>>>(Win_w, u, tbuf);
  k_norm<<<1, 256, 0, stream>>>(tbuf, sbuf);
  k_prep2<<<512, 256, 0, stream>>>(Win_w, tbuf, sbuf);
  k_xproj<<<256, 256, 0, stream>>>(x16, wi16, Win_b, sbuf, xp, h16a);
  k_persist<<<256, 512, 0, stream>>>(w16, b0, b1, b2, xp, h16a, h16b, cnt);
  k_head<<<128, 256, 0, stream>>>(h16a, hw16, headb, (float*)d_out);
}